// Round 9
// baseline (451.734 us; speedup 1.0000x reference)
//
#include <hip/hip_runtime.h>

#define N_NODES 100000
#define N_EDGES 300000
#define NB 1024

#define CAP_F1 16384        // F1 = boundary ∪ N(boundary), expected ~7.2k
#define CAP_F2 65536        // F2 = F1 ∪ N(F1), expected ~41k
#define K_ADJ  64           // per-slot adjacency cap (deg ~ Poisson(6))

// padded counter indices (64B apart)
#define CNT_F1 0
#define CNT_F2 16

// ---------------- workspace layout (float offsets) ----------------
#define OFF_X1C     0u          // CAP_F2*64  = 4,194,304
#define OFF_X2C     4194304u    // CAP_F1*128 = 2,097,152
#define OFF_X3B     6291456u    // 1024*256   = 262,144
// ---- zero region ----
#define OFF_AGG0C   6553600u    // CAP_F2*4   = 262,144
#define OFF_AGG1C   6815744u    // CAP_F1*64  = 1,048,576
#define OFF_AGG2C   7864320u    // 1024*128   = 131,072
#define OFF_POOL    7995392u    // 256
#define OFF_CNT     7995648u    // 64
#define OFF_DEGF2   7995712u    // 65,536
#define OFF_DEGF1   8061248u    // 16,384
#define OFF_DEGB    8077632u    // 1,024
#define ZERO_END    8078656u
#define ZERO_BYTES  ((ZERO_END - OFF_AGG0C) * 4u)
// ---- 0xFF region (slot maps = -1) ----
#define OFF_SLOTB   8078656u    // 100,000
#define OFF_SLOTF1  8178656u    // 100,000
#define OFF_SLOTF2  8278656u    // 100,000
#define FF_BYTES    (300000u * 4u)
// ---- no-init region ----
#define OFF_LISTF1  8378656u    // 16,384
#define OFF_LISTF2  8395040u    // 65,536
#define OFF_ADJ0    8460576u    // CAP_F2*64 = 4,194,304 (node ids)
#define OFF_ADJF1   12654880u   // CAP_F1*64 = 1,048,576 (F2 slots)
#define OFF_ADJB    13703456u   // 1024*64   = 65,536    (F1 slots)
#define OFF_IDXX2   13768992u   // 1024
#define OFF_IDXA2   13770016u   // 1024
#define OFF_F1F2    13771040u   // 16,384 (F1 slot -> F2 slot)
#define OFF_BMEAN   13787424u   // 3

// boundary mean of vs -> bmean[3]
__global__ void bmean_kernel(const float* __restrict__ vs, const int* __restrict__ bidx,
                             float* __restrict__ bmean) {
    int tid = threadIdx.x;
    float s0 = 0.f, s1 = 0.f, s2 = 0.f;
    for (int i = tid; i < NB; i += 256) {
        int n = bidx[i];
        s0 += vs[n * 3 + 0];
        s1 += vs[n * 3 + 1];
        s2 += vs[n * 3 + 2];
    }
    for (int off = 32; off > 0; off >>= 1) {
        s0 += __shfl_down(s0, off);
        s1 += __shfl_down(s1, off);
        s2 += __shfl_down(s2, off);
    }
    __shared__ float red[4][3];
    int wave = tid >> 6;
    if ((tid & 63) == 0) { red[wave][0] = s0; red[wave][1] = s1; red[wave][2] = s2; }
    __syncthreads();
    if (tid == 0) {
        float t0 = 0, t1 = 0, t2 = 0;
        for (int w = 0; w < 4; w++) { t0 += red[w][0]; t1 += red[w][1]; t2 += red[w][2]; }
        bmean[0] = t0 / NB; bmean[1] = t1 / NB; bmean[2] = t2 / NB;
    }
}

// wave-aggregated set claim: CAS per node (dedup), ONE counter atomic per wave.
// All 64 lanes must reach this call.
__device__ __forceinline__ void claim(bool want, int node, int* __restrict__ slot,
                                      int* __restrict__ list, int* __restrict__ cnt, int cap) {
    bool won = false;
    if (want) won = (atomicCAS(&slot[node], -1, -2) == -1);
    unsigned long long m = __ballot(won);
    if (m == 0ull) return;
    int lane = threadIdx.x & 63;
    int leader = __ffsll((unsigned long long)m) - 1;
    int base = 0;
    if (lane == leader) base = atomicAdd(cnt, __popcll(m));
    base = __shfl(base, leader);
    if (won) {
        int p = base + __popcll(m & ((1ull << lane) - 1));
        if (p < cap) { list[p] = node; slot[node] = p; }
        // overflow: slot stays -2 (excluded)
    }
}

// A: slotB map + seed F1 and F2 with boundary nodes
__global__ void mark_boundary_kernel(const int* __restrict__ bidx, int* __restrict__ slotB,
                                     int* __restrict__ slotF1, int* __restrict__ listF1,
                                     int* __restrict__ slotF2, int* __restrict__ listF2,
                                     int* __restrict__ cnt) {
    int i = blockIdx.x * 256 + threadIdx.x;
    bool valid = i < NB;
    int n = valid ? bidx[i] : 0;
    if (valid) slotB[n] = i;   // duplicates: any winner, consistent everywhere
    claim(valid, n, slotF1, listF1, cnt + CNT_F1, CAP_F1);
    claim(valid, n, slotF2, listF2, cnt + CNT_F2, CAP_F2);
}

// B: F1 += N(boundary) (and keep F2 ⊇ F1)
__global__ void expand_f1_kernel(const int2* __restrict__ edges, const int* __restrict__ slotB,
                                 int* __restrict__ slotF1, int* __restrict__ listF1,
                                 int* __restrict__ slotF2, int* __restrict__ listF2,
                                 int* __restrict__ cnt) {
    int e = blockIdx.x * 256 + threadIdx.x;
    bool valid = e < N_EDGES;
    int2 ed = valid ? edges[e] : make_int2(0, 0);
    bool wy = valid && (slotB[ed.y] >= 0);
    bool wx = valid && (slotB[ed.x] >= 0);
    claim(wy, ed.x, slotF1, listF1, cnt + CNT_F1, CAP_F1);
    claim(wx, ed.y, slotF1, listF1, cnt + CNT_F1, CAP_F1);
    claim(wy, ed.x, slotF2, listF2, cnt + CNT_F2, CAP_F2);
    claim(wx, ed.y, slotF2, listF2, cnt + CNT_F2, CAP_F2);
}

// C: F2 += N(F1)
__global__ void expand_f2_kernel(const int2* __restrict__ edges, const int* __restrict__ slotF1,
                                 int* __restrict__ slotF2, int* __restrict__ listF2,
                                 int* __restrict__ cnt) {
    int e = blockIdx.x * 256 + threadIdx.x;
    bool valid = e < N_EDGES;
    int2 ed = valid ? edges[e] : make_int2(0, 0);
    bool wy = valid && (slotF1[ed.y] >= 0);
    bool wx = valid && (slotF1[ed.x] >= 0);
    claim(wy, ed.x, slotF2, listF2, cnt + CNT_F2, CAP_F2);
    claim(wx, ed.y, slotF2, listF2, cnt + CNT_F2, CAP_F2);
}

__device__ __forceinline__ void adj_append(int* __restrict__ deg, int* __restrict__ adj,
                                           int slot, int src) {
    int pos = atomicAdd(&deg[slot], 1);
    if (pos < K_ADJ) adj[slot * K_ADJ + pos] = src;
}

// D: one edge pass -> per-slot adjacency lists (gather form of all three aggs)
__global__ void build_adj_kernel(const int2* __restrict__ edges,
                                 const int* __restrict__ slotB, const int* __restrict__ slotF1,
                                 const int* __restrict__ slotF2,
                                 int* __restrict__ degF2, int* __restrict__ adj0,
                                 int* __restrict__ degF1, int* __restrict__ adjF1,
                                 int* __restrict__ degB, int* __restrict__ adjB) {
    int e = blockIdx.x * 256 + threadIdx.x;
    if (e >= N_EDGES) return;
    int2 ed = edges[e];
    int x = ed.x, y = ed.y;
    int sxB = slotB[x], syB = slotB[y];
    int sxF1 = slotF1[x], syF1 = slotF1[y];
    int sxF2 = slotF2[x], syF2 = slotF2[y];
    if (syF2 >= 0) adj_append(degF2, adj0, syF2, x);     // agg0 sources: raw node ids
    if (sxF2 >= 0) adj_append(degF2, adj0, sxF2, y);
    if (syF1 >= 0) adj_append(degF1, adjF1, syF1, sxF2); // agg1 sources: F2 slots (x ∈ N(F1) ⊆ F2)
    if (sxF1 >= 0) adj_append(degF1, adjF1, sxF1, syF2);
    if (syB >= 0)  adj_append(degB, adjB, syB, sxF1);    // agg2 sources: F1 slots (x ∈ N(B) ⊆ F1)
    if (sxB >= 0)  adj_append(degB, adjB, sxB, syF1);
}

// E: gather index arrays for conv2
__global__ void conv2_idx_kernel(const int* __restrict__ bidx, const int* __restrict__ slotB,
                                 const int* __restrict__ slotF1,
                                 int* __restrict__ idxx, int* __restrict__ idxa) {
    int i = blockIdx.x * 256 + threadIdx.x;
    if (i >= NB) return;
    int n = bidx[i];
    idxx[i] = slotF1[n];
    idxa[i] = slotB[n];
}

// F: F1 slot -> F2 slot map (x1c rows for conv1)
__global__ void f1f2_kernel(const int* __restrict__ listF1, const int* __restrict__ slotF2,
                            const int* __restrict__ cnt, int* __restrict__ f1f2) {
    int i = blockIdx.x * 256 + threadIdx.x;
    int n = min(cnt[CNT_F1], CAP_F1);
    if (i < n) f1f2[i] = slotF2[listF1[i]];
}

// gather agg0 (3ch) per F2 slot: thread per slot
__global__ void gather0_kernel(const float* __restrict__ vs, const int* __restrict__ adj0,
                               const int* __restrict__ degF2, const int* __restrict__ cnt,
                               float* __restrict__ agg0c) {
    int s = blockIdx.x * 256 + threadIdx.x;
    int n = min(cnt[CNT_F2], CAP_F2);
    if (s >= n) return;
    int deg = min(degF2[s], K_ADJ);
    float a0 = 0.f, a1 = 0.f, a2 = 0.f;
    for (int d = 0; d < deg; d++) {
        int src = adj0[s * K_ADJ + d];
        a0 += vs[src * 3 + 0];
        a1 += vs[src * 3 + 1];
        a2 += vs[src * 3 + 2];
    }
    agg0c[s * 4 + 0] = a0; agg0c[s * 4 + 1] = a1; agg0c[s * 4 + 2] = a2;
}

// conv0 on compact F2 rows: 3 -> 64, relu. block = 4 slots x 64 couts
__global__ void conv0c_kernel(const float* __restrict__ vs, const int* __restrict__ listF2,
                              const float* __restrict__ agg0c,
                              const float* __restrict__ Ws, const float* __restrict__ Wn,
                              const float* __restrict__ b, const int* __restrict__ cnt,
                              float* __restrict__ x1c) {
    int nF2 = min(cnt[CNT_F2], CAP_F2);
    if ((int)blockIdx.x * 4 >= nF2) return;
    __shared__ float ws_l[192], wn_l[192], b_l[64];
    int tid = threadIdx.x;
    if (tid < 192) { ws_l[tid] = Ws[tid]; wn_l[tid] = Wn[tid]; }
    if (tid < 64) b_l[tid] = b[tid];
    __syncthreads();
    int g = blockIdx.x * 4 + (tid >> 6);
    int j = tid & 63;
    if (g >= nF2) return;
    int n = listF2[g];
    float x0 = vs[n * 3 + 0], x1v = vs[n * 3 + 1], x2v = vs[n * 3 + 2];
    float a0 = agg0c[g * 4 + 0], a1 = agg0c[g * 4 + 1], a2 = agg0c[g * 4 + 2];
    float acc = b_l[j];
    acc = fmaf(x0, ws_l[0 * 64 + j], acc);
    acc = fmaf(x1v, ws_l[1 * 64 + j], acc);
    acc = fmaf(x2v, ws_l[2 * 64 + j], acc);
    acc = fmaf(a0, wn_l[0 * 64 + j], acc);
    acc = fmaf(a1, wn_l[1 * 64 + j], acc);
    acc = fmaf(a2, wn_l[2 * 64 + j], acc);
    x1c[g * 64 + j] = fmaxf(acc, 0.f);
}

// gather agg1 (64ch) per F1 slot: wave per slot, lane = channel
__global__ __launch_bounds__(256) void gather1_kernel(const float* __restrict__ x1c,
                                                      const int* __restrict__ adjF1,
                                                      const int* __restrict__ degF1,
                                                      const int* __restrict__ cnt,
                                                      float* __restrict__ agg1c) {
    int wslot = blockIdx.x * 4 + (threadIdx.x >> 6);
    int lane = threadIdx.x & 63;
    int n = min(cnt[CNT_F1], CAP_F1);
    if (wslot >= n) return;
    int deg = min(degF1[wslot], K_ADJ);
    float acc = 0.f;
    for (int d = 0; d < deg; d++) {
        int src = adjF1[wslot * K_ADJ + d];
        if (src >= 0) acc += x1c[src * 64 + lane];
    }
    agg1c[wslot * 64 + lane] = acc;
}

// gather agg2 (128ch) per boundary slot: wave per slot, 2 channel halves
__global__ __launch_bounds__(256) void gather2_kernel(const float* __restrict__ x2c,
                                                      const int* __restrict__ adjB,
                                                      const int* __restrict__ degB,
                                                      float* __restrict__ agg2c) {
    int wslot = blockIdx.x * 4 + (threadIdx.x >> 6);   // < 1024
    int lane = threadIdx.x & 63;
    int deg = min(degB[wslot], K_ADJ);
    float a0 = 0.f, a1 = 0.f;
    for (int d = 0; d < deg; d++) {
        int src = adjB[wslot * K_ADJ + d];
        if (src >= 0) {
            a0 += x2c[src * 128 + lane];
            a1 += x2c[src * 128 + 64 + lane];
        }
    }
    agg2c[wslot * 128 + lane] = a0;
    agg2c[wslot * 128 + 64 + lane] = a1;
}

// generic conv: CIN -> COUT, relu, 64-row tile in LDS.
template <int CIN, int COUT>
__global__ __launch_bounds__(256) void convN_kernel(
    const float* __restrict__ x, const float* __restrict__ agg,
    const float* __restrict__ Ws, const float* __restrict__ Wn,
    const float* __restrict__ b, float* __restrict__ out,
    const int* __restrict__ idxx, const int* __restrict__ idxa,
    int nrows_max, const int* __restrict__ nrows_dev) {
    const int JT = COUT / 64;
    __shared__ float xs[64 * CIN];
    __shared__ float as[64 * CIN];
    int nrows = nrows_max;
    if (nrows_dev) { int nd = nrows_dev[0]; nrows = nd < nrows ? nd : nrows; }
    int tid = threadIdx.x;
    int gbase = blockIdx.x * 64;
    if (gbase >= nrows) return;
    for (int i = tid; i < 64 * CIN; i += 256) {
        int nl = i / CIN;
        int c = i % CIN;
        int ng = gbase + nl;
        float xv = 0.f, av = 0.f;
        if (ng < nrows) {
            int rowx = idxx ? idxx[ng] : ng;
            int rowa = idxa ? idxa[ng] : ng;
            xv = x[rowx * CIN + c];
            av = agg[rowa * CIN + c];
        }
        xs[i] = xv;
        as[i] = av;
    }
    __syncthreads();
    int j = tid & 63;
    int g = tid >> 6;
    float acc[16][JT];
    #pragma unroll
    for (int jt = 0; jt < JT; jt++) {
        float bv = b[jt * 64 + j];
        #pragma unroll
        for (int k = 0; k < 16; k++) acc[k][jt] = bv;
    }
    #pragma unroll 4
    for (int c = 0; c < CIN; c++) {
        float wsv[JT], wnv[JT];
        #pragma unroll
        for (int jt = 0; jt < JT; jt++) {
            wsv[jt] = Ws[c * COUT + jt * 64 + j];
            wnv[jt] = Wn[c * COUT + jt * 64 + j];
        }
        #pragma unroll
        for (int k = 0; k < 16; k++) {
            float xv = xs[(g * 16 + k) * CIN + c];
            float av = as[(g * 16 + k) * CIN + c];
            #pragma unroll
            for (int jt = 0; jt < JT; jt++)
                acc[k][jt] = fmaf(xv, wsv[jt], fmaf(av, wnv[jt], acc[k][jt]));
        }
    }
    #pragma unroll
    for (int k = 0; k < 16; k++) {
        int ng = gbase + g * 16 + k;
        if (ng < nrows) {
            #pragma unroll
            for (int jt = 0; jt < JT; jt++)
                out[ng * COUT + jt * 64 + j] = fmaxf(acc[k][jt], 0.f);
        }
    }
}

// pooled sum over 1024 boundary rows of x3b (compact 1024x256)
__global__ void pool_kernel(const float* __restrict__ x3b, float* __restrict__ pooled) {
    int j = threadIdx.x;
    int r0 = blockIdx.x * 32;
    float s = 0.f;
    for (int r = 0; r < 32; r++) s += x3b[(r0 + r) * 256 + j];
    atomicAdd(&pooled[j], s);
}

// head: pooled/1024 -> fc(relu) -> out(12) + bmean broadcast
__global__ void head_kernel(const float* __restrict__ pooled_sum, const float* __restrict__ bmean,
                            const float* __restrict__ Wd, const float* __restrict__ bd,
                            const float* __restrict__ Wo, const float* __restrict__ bo,
                            float* __restrict__ out) {
    __shared__ float p_l[256], h_l[256];
    int tid = threadIdx.x;
    p_l[tid] = pooled_sum[tid] * (1.0f / NB);
    __syncthreads();
    float acc = bd[tid];
    for (int c = 0; c < 256; c++) acc = fmaf(p_l[c], Wd[c * 256 + tid], acc);
    h_l[tid] = fmaxf(acc, 0.f);
    __syncthreads();
    if (tid < 12) {
        float o = bo[tid];
        for (int c = 0; c < 256; c++) o = fmaf(h_l[c], Wo[c * 12 + tid], o);
        out[tid] = o + bmean[tid % 3];
    }
}

extern "C" void kernel_launch(void* const* d_in, const int* in_sizes, int n_in,
                              void* d_out, int out_size, void* d_ws, size_t ws_size,
                              hipStream_t stream) {
    const float* vs    = (const float*)d_in[0];
    const int2*  edges = (const int2*)d_in[1];
    const int*   bidx  = (const int*)d_in[2];
    const float* Ws0 = (const float*)d_in[4];
    const float* Wn0 = (const float*)d_in[5];
    const float* b0  = (const float*)d_in[6];
    const float* Ws1 = (const float*)d_in[7];
    const float* Wn1 = (const float*)d_in[8];
    const float* b1  = (const float*)d_in[9];
    const float* Ws2 = (const float*)d_in[10];
    const float* Wn2 = (const float*)d_in[11];
    const float* b2  = (const float*)d_in[12];
    const float* Wd  = (const float*)d_in[13];
    const float* bd  = (const float*)d_in[14];
    const float* Wo  = (const float*)d_in[15];
    const float* bo  = (const float*)d_in[16];

    float* ws = (float*)d_ws;
    float* x1c    = ws + OFF_X1C;
    float* x2c    = ws + OFF_X2C;
    float* x3b    = ws + OFF_X3B;
    float* agg0c  = ws + OFF_AGG0C;
    float* agg1c  = ws + OFF_AGG1C;
    float* agg2c  = ws + OFF_AGG2C;
    float* pooled = ws + OFF_POOL;
    int*   cnt    = (int*)(ws + OFF_CNT);
    int*   degF2  = (int*)(ws + OFF_DEGF2);
    int*   degF1  = (int*)(ws + OFF_DEGF1);
    int*   degB   = (int*)(ws + OFF_DEGB);
    int*   slotB  = (int*)(ws + OFF_SLOTB);
    int*   slotF1 = (int*)(ws + OFF_SLOTF1);
    int*   slotF2 = (int*)(ws + OFF_SLOTF2);
    int*   listF1 = (int*)(ws + OFF_LISTF1);
    int*   listF2 = (int*)(ws + OFF_LISTF2);
    int*   adj0   = (int*)(ws + OFF_ADJ0);
    int*   adjF1  = (int*)(ws + OFF_ADJF1);
    int*   adjB   = (int*)(ws + OFF_ADJB);
    int*   idxx2  = (int*)(ws + OFF_IDXX2);
    int*   idxa2  = (int*)(ws + OFF_IDXA2);
    int*   f1f2   = (int*)(ws + OFF_F1F2);
    float* bmean  = ws + OFF_BMEAN;
    float* outp   = (float*)d_out;

    const int EB = (N_EDGES + 255) / 256;

    hipMemsetAsync(ws + OFF_SLOTB, 0xFF, FF_BYTES, stream);
    hipMemsetAsync(ws + OFF_AGG0C, 0, ZERO_BYTES, stream);

    bmean_kernel<<<1, 256, 0, stream>>>(vs, bidx, bmean);

    // frontier construction: B -> F1 -> F2
    mark_boundary_kernel<<<(NB + 255) / 256, 256, 0, stream>>>(
        bidx, slotB, slotF1, listF1, slotF2, listF2, cnt);
    expand_f1_kernel<<<EB, 256, 0, stream>>>(edges, slotB, slotF1, listF1, slotF2, listF2, cnt);
    expand_f2_kernel<<<EB, 256, 0, stream>>>(edges, slotF1, slotF2, listF2, cnt);
    build_adj_kernel<<<EB, 256, 0, stream>>>(edges, slotB, slotF1, slotF2,
                                             degF2, adj0, degF1, adjF1, degB, adjB);
    conv2_idx_kernel<<<(NB + 255) / 256, 256, 0, stream>>>(bidx, slotB, slotF1, idxx2, idxa2);
    f1f2_kernel<<<CAP_F1 / 256, 256, 0, stream>>>(listF1, slotF2, cnt, f1f2);

    // layer 0 on F2 (gather, no fp atomics)
    gather0_kernel<<<CAP_F2 / 256, 256, 0, stream>>>(vs, adj0, degF2, cnt, agg0c);
    conv0c_kernel<<<CAP_F2 / 4, 256, 0, stream>>>(vs, listF2, agg0c, Ws0, Wn0, b0, cnt, x1c);

    // layer 1 on F1
    gather1_kernel<<<CAP_F1 / 4, 256, 0, stream>>>(x1c, adjF1, degF1, cnt, agg1c);
    convN_kernel<64, 128><<<CAP_F1 / 64, 256, 0, stream>>>(
        x1c, agg1c, Ws1, Wn1, b1, x2c, f1f2, nullptr, CAP_F1, cnt + CNT_F1);

    // layer 2 on boundary
    gather2_kernel<<<NB / 4, 256, 0, stream>>>(x2c, adjB, degB, agg2c);
    convN_kernel<128, 256><<<NB / 64, 256, 0, stream>>>(
        x2c, agg2c, Ws2, Wn2, b2, x3b, idxx2, idxa2, NB, nullptr);

    // head
    pool_kernel<<<32, 256, 0, stream>>>(x3b, pooled);
    head_kernel<<<1, 256, 0, stream>>>(pooled, bmean, Wd, bd, Wo, bo, outp);
}

// Round 10
// 270.718 us; speedup vs baseline: 1.6687x; 1.6687x over previous
//
#include <hip/hip_runtime.h>

#define N_NODES 100000
#define N_EDGES 300000
#define NB 1024

#define CAP_F1 16384        // F1 = boundary ∪ N(boundary), expected ~7.2k
#define CAP_F2 65536        // F2 = F1 ∪ N(F1), expected ~41k
#define K_ADJ  64           // per-slot adjacency cap (deg ~ Poisson(6))

// padded counter indices (64B apart)
#define CNT_F1 0
#define CNT_F2 16

// ---------------- workspace layout (float offsets) ----------------
#define OFF_X1C     0u          // CAP_F2*64  = 4,194,304
#define OFF_X2C     4194304u    // CAP_F1*128 = 2,097,152
#define OFF_X3B     6291456u    // 1024*256   = 262,144
#define OFF_AGG0C   6553600u    // CAP_F2*4   = 262,144   (fully written by gather0)
#define OFF_AGG1C   6815744u    // CAP_F1*64  = 1,048,576 (fully written by gather1)
#define OFF_AGG2C   7864320u    // 1024*128   = 131,072   (fully written by gather2)
// ---- zero region ----
#define OFF_POOL    7995392u    // 256
#define OFF_CNT     7995648u    // 64
#define OFF_DEGF2   7995712u    // 65,536
#define OFF_DEGF1   8061248u    // 16,384
#define OFF_DEGB    8077632u    // 1,024
#define OFF_MF1     8078656u    // 100,000
#define OFF_MF2     8178656u    // 100,000
#define ZERO_END    8278656u
#define ZERO_BYTES  ((ZERO_END - OFF_POOL) * 4u)
// ---- 0xFF region ----
#define OFF_SLOTB   8278656u    // 100,000
#define FF_BYTES    (100000u * 4u)
// ---- no-init region (fully written before read) ----
#define OFF_SLOTF1  8378656u    // 100,000 (compactF1 writes all)
#define OFF_SLOTF2  8478656u    // 100,000 (compactF2 writes all)
#define OFF_LISTF1  8578656u    // 16,384
#define OFF_LISTF2  8595040u    // 65,536
#define OFF_ADJ0    8660576u    // CAP_F2*64 = 4,194,304 (node ids)
#define OFF_ADJF1   12854880u   // CAP_F1*64 = 1,048,576 (F2 slots)
#define OFF_ADJB    13903456u   // 1024*64   = 65,536    (F1 slots)
#define OFF_IDXX2   13968992u   // 1024
#define OFF_IDXA2   13970016u   // 1024
#define OFF_F1F2    13971040u   // 16,384 (F1 slot -> F2 slot)
#define OFF_BMEAN   13987424u   // 3

// boundary mean of vs -> bmean[3]
__global__ void bmean_kernel(const float* __restrict__ vs, const int* __restrict__ bidx,
                             float* __restrict__ bmean) {
    int tid = threadIdx.x;
    float s0 = 0.f, s1 = 0.f, s2 = 0.f;
    for (int i = tid; i < NB; i += 256) {
        int n = bidx[i];
        s0 += vs[n * 3 + 0];
        s1 += vs[n * 3 + 1];
        s2 += vs[n * 3 + 2];
    }
    for (int off = 32; off > 0; off >>= 1) {
        s0 += __shfl_down(s0, off);
        s1 += __shfl_down(s1, off);
        s2 += __shfl_down(s2, off);
    }
    __shared__ float red[4][3];
    int wave = tid >> 6;
    if ((tid & 63) == 0) { red[wave][0] = s0; red[wave][1] = s1; red[wave][2] = s2; }
    __syncthreads();
    if (tid == 0) {
        float t0 = 0, t1 = 0, t2 = 0;
        for (int w = 0; w < 4; w++) { t0 += red[w][0]; t1 += red[w][1]; t2 += red[w][2]; }
        bmean[0] = t0 / NB; bmean[1] = t1 / NB; bmean[2] = t2 / NB;
    }
}

// A: slotB map (plain stores; duplicates -> any winner, consistent everywhere)
__global__ void mark_b_kernel(const int* __restrict__ bidx, int* __restrict__ slotB) {
    int i = blockIdx.x * 256 + threadIdx.x;
    if (i < NB) slotB[bidx[i]] = i;
}

// B: mark neighbors of {src set}: mark[x] = 1 if other endpoint in set.
// Idempotent plain stores — no atomics, no counter.
__global__ void scan_mark_kernel(const int2* __restrict__ edges, const int* __restrict__ srcSlot,
                                 int* __restrict__ mark) {
    int e = blockIdx.x * 256 + threadIdx.x;
    if (e >= N_EDGES) return;
    int2 ed = edges[e];
    if (srcSlot[ed.y] >= 0) mark[ed.x] = 1;
    if (srcSlot[ed.x] >= 0) mark[ed.y] = 1;
}

// C: dense compact over all nodes: want = mark[i] || aux[i]>=0.
// Block-aggregated allocation: ONE counter atomic per block (391 total).
// Writes slot[i] for EVERY node (-1 if not wanted) -> no FF-init needed.
// If f1map!=nullptr: for nodes with aux[i]>=0 (F1 members), f1map[aux[i]] = slot.
__global__ __launch_bounds__(256) void compact_kernel(
        const int* __restrict__ mark, const int* __restrict__ aux,
        int* __restrict__ slot, int* __restrict__ list,
        int* __restrict__ cnt, int cap, int* __restrict__ f1map) {
    int i = blockIdx.x * 256 + threadIdx.x;
    int auxv = -1;
    bool want = false;
    if (i < N_NODES) {
        auxv = aux[i];
        want = (mark[i] != 0) || (auxv >= 0);
    }
    int wave = threadIdx.x >> 6, lane = threadIdx.x & 63;
    unsigned long long m = __ballot(want);
    int rank = __popcll(m & ((1ull << lane) - 1));
    __shared__ int s_w[4];
    __shared__ int s_base;
    if (lane == 0) s_w[wave] = __popcll(m);
    __syncthreads();
    if (threadIdx.x == 0) {
        int s = 0;
        #pragma unroll
        for (int w = 0; w < 4; w++) { int v = s_w[w]; s_w[w] = s; s += v; }
        s_base = s ? atomicAdd(cnt, s) : 0;
    }
    __syncthreads();
    if (i < N_NODES) {
        int p = -1;
        if (want) {
            p = s_base + s_w[wave] + rank;
            if (p < cap) list[p] = i; else p = -1;   // overflow -> excluded
        }
        slot[i] = p;
        if (f1map && auxv >= 0) f1map[auxv] = p;     // F1 slot -> F2 slot
    }
}

__device__ __forceinline__ void adj_append(int* __restrict__ deg, int* __restrict__ adj,
                                           int slot, int src) {
    int pos = atomicAdd(&deg[slot], 1);
    if (pos < K_ADJ) adj[slot * K_ADJ + pos] = src;
}

// D: one edge pass -> per-slot adjacency lists (distributed atomics — proven cheap)
__global__ void build_adj_kernel(const int2* __restrict__ edges,
                                 const int* __restrict__ slotB, const int* __restrict__ slotF1,
                                 const int* __restrict__ slotF2,
                                 int* __restrict__ degF2, int* __restrict__ adj0,
                                 int* __restrict__ degF1, int* __restrict__ adjF1,
                                 int* __restrict__ degB, int* __restrict__ adjB) {
    int e = blockIdx.x * 256 + threadIdx.x;
    if (e >= N_EDGES) return;
    int2 ed = edges[e];
    int x = ed.x, y = ed.y;
    int sxB = slotB[x], syB = slotB[y];
    int sxF1 = slotF1[x], syF1 = slotF1[y];
    int sxF2 = slotF2[x], syF2 = slotF2[y];
    if (syF2 >= 0) adj_append(degF2, adj0, syF2, x);     // agg0 sources: raw node ids
    if (sxF2 >= 0) adj_append(degF2, adj0, sxF2, y);
    if (syF1 >= 0) adj_append(degF1, adjF1, syF1, sxF2); // agg1 sources: F2 slots (N(F1) ⊆ F2)
    if (sxF1 >= 0) adj_append(degF1, adjF1, sxF1, syF2);
    if (syB >= 0)  adj_append(degB, adjB, syB, sxF1);    // agg2 sources: F1 slots (N(B) ⊆ F1)
    if (sxB >= 0)  adj_append(degB, adjB, sxB, syF1);
}

// E: gather index arrays for conv2 (per boundary position, duplicates handled)
__global__ void conv2_idx_kernel(const int* __restrict__ bidx, const int* __restrict__ slotB,
                                 const int* __restrict__ slotF1,
                                 int* __restrict__ idxx, int* __restrict__ idxa) {
    int i = blockIdx.x * 256 + threadIdx.x;
    if (i >= NB) return;
    int n = bidx[i];
    idxx[i] = slotF1[n];
    idxa[i] = slotB[n];
}

// gather agg0 (3ch) per F2 slot: thread per slot
__global__ void gather0_kernel(const float* __restrict__ vs, const int* __restrict__ adj0,
                               const int* __restrict__ degF2, const int* __restrict__ cnt,
                               float* __restrict__ agg0c) {
    int s = blockIdx.x * 256 + threadIdx.x;
    int n = min(cnt[CNT_F2], CAP_F2);
    if (s >= n) return;
    int deg = min(degF2[s], K_ADJ);
    float a0 = 0.f, a1 = 0.f, a2 = 0.f;
    for (int d = 0; d < deg; d++) {
        int src = adj0[s * K_ADJ + d];
        a0 += vs[src * 3 + 0];
        a1 += vs[src * 3 + 1];
        a2 += vs[src * 3 + 2];
    }
    agg0c[s * 4 + 0] = a0; agg0c[s * 4 + 1] = a1; agg0c[s * 4 + 2] = a2;
}

// conv0 on compact F2 rows: 3 -> 64, relu. block = 4 slots x 64 couts
__global__ void conv0c_kernel(const float* __restrict__ vs, const int* __restrict__ listF2,
                              const float* __restrict__ agg0c,
                              const float* __restrict__ Ws, const float* __restrict__ Wn,
                              const float* __restrict__ b, const int* __restrict__ cnt,
                              float* __restrict__ x1c) {
    int nF2 = min(cnt[CNT_F2], CAP_F2);
    if ((int)blockIdx.x * 4 >= nF2) return;
    __shared__ float ws_l[192], wn_l[192], b_l[64];
    int tid = threadIdx.x;
    if (tid < 192) { ws_l[tid] = Ws[tid]; wn_l[tid] = Wn[tid]; }
    if (tid < 64) b_l[tid] = b[tid];
    __syncthreads();
    int g = blockIdx.x * 4 + (tid >> 6);
    int j = tid & 63;
    if (g >= nF2) return;
    int n = listF2[g];
    float x0 = vs[n * 3 + 0], x1v = vs[n * 3 + 1], x2v = vs[n * 3 + 2];
    float a0 = agg0c[g * 4 + 0], a1 = agg0c[g * 4 + 1], a2 = agg0c[g * 4 + 2];
    float acc = b_l[j];
    acc = fmaf(x0, ws_l[0 * 64 + j], acc);
    acc = fmaf(x1v, ws_l[1 * 64 + j], acc);
    acc = fmaf(x2v, ws_l[2 * 64 + j], acc);
    acc = fmaf(a0, wn_l[0 * 64 + j], acc);
    acc = fmaf(a1, wn_l[1 * 64 + j], acc);
    acc = fmaf(a2, wn_l[2 * 64 + j], acc);
    x1c[g * 64 + j] = fmaxf(acc, 0.f);
}

// gather agg1 (64ch) per F1 slot: wave per slot, lane = channel
__global__ __launch_bounds__(256) void gather1_kernel(const float* __restrict__ x1c,
                                                      const int* __restrict__ adjF1,
                                                      const int* __restrict__ degF1,
                                                      const int* __restrict__ cnt,
                                                      float* __restrict__ agg1c) {
    int wslot = blockIdx.x * 4 + (threadIdx.x >> 6);
    int lane = threadIdx.x & 63;
    int n = min(cnt[CNT_F1], CAP_F1);
    if (wslot >= n) return;
    int deg = min(degF1[wslot], K_ADJ);
    float acc = 0.f;
    for (int d = 0; d < deg; d++) {
        int src = adjF1[wslot * K_ADJ + d];
        if (src >= 0) acc += x1c[src * 64 + lane];
    }
    agg1c[wslot * 64 + lane] = acc;
}

// gather agg2 (128ch) per boundary slot: wave per slot, 2 channel halves
__global__ __launch_bounds__(256) void gather2_kernel(const float* __restrict__ x2c,
                                                      const int* __restrict__ adjB,
                                                      const int* __restrict__ degB,
                                                      float* __restrict__ agg2c) {
    int wslot = blockIdx.x * 4 + (threadIdx.x >> 6);   // < 1024
    int lane = threadIdx.x & 63;
    int deg = min(degB[wslot], K_ADJ);
    float a0 = 0.f, a1 = 0.f;
    for (int d = 0; d < deg; d++) {
        int src = adjB[wslot * K_ADJ + d];
        if (src >= 0) {
            a0 += x2c[src * 128 + lane];
            a1 += x2c[src * 128 + 64 + lane];
        }
    }
    agg2c[wslot * 128 + lane] = a0;
    agg2c[wslot * 128 + 64 + lane] = a1;
}

// generic conv: CIN -> COUT, relu, 64-row tile in LDS.
template <int CIN, int COUT>
__global__ __launch_bounds__(256) void convN_kernel(
    const float* __restrict__ x, const float* __restrict__ agg,
    const float* __restrict__ Ws, const float* __restrict__ Wn,
    const float* __restrict__ b, float* __restrict__ out,
    const int* __restrict__ idxx, const int* __restrict__ idxa,
    int nrows_max, const int* __restrict__ nrows_dev) {
    const int JT = COUT / 64;
    __shared__ float xs[64 * CIN];
    __shared__ float as[64 * CIN];
    int nrows = nrows_max;
    if (nrows_dev) { int nd = nrows_dev[0]; nrows = nd < nrows ? nd : nrows; }
    int tid = threadIdx.x;
    int gbase = blockIdx.x * 64;
    if (gbase >= nrows) return;
    for (int i = tid; i < 64 * CIN; i += 256) {
        int nl = i / CIN;
        int c = i % CIN;
        int ng = gbase + nl;
        float xv = 0.f, av = 0.f;
        if (ng < nrows) {
            int rowx = idxx ? idxx[ng] : ng;
            int rowa = idxa ? idxa[ng] : ng;
            xv = x[rowx * CIN + c];
            av = agg[rowa * CIN + c];
        }
        xs[i] = xv;
        as[i] = av;
    }
    __syncthreads();
    int j = tid & 63;
    int g = tid >> 6;
    float acc[16][JT];
    #pragma unroll
    for (int jt = 0; jt < JT; jt++) {
        float bv = b[jt * 64 + j];
        #pragma unroll
        for (int k = 0; k < 16; k++) acc[k][jt] = bv;
    }
    #pragma unroll 4
    for (int c = 0; c < CIN; c++) {
        float wsv[JT], wnv[JT];
        #pragma unroll
        for (int jt = 0; jt < JT; jt++) {
            wsv[jt] = Ws[c * COUT + jt * 64 + j];
            wnv[jt] = Wn[c * COUT + jt * 64 + j];
        }
        #pragma unroll
        for (int k = 0; k < 16; k++) {
            float xv = xs[(g * 16 + k) * CIN + c];
            float av = as[(g * 16 + k) * CIN + c];
            #pragma unroll
            for (int jt = 0; jt < JT; jt++)
                acc[k][jt] = fmaf(xv, wsv[jt], fmaf(av, wnv[jt], acc[k][jt]));
        }
    }
    #pragma unroll
    for (int k = 0; k < 16; k++) {
        int ng = gbase + g * 16 + k;
        if (ng < nrows) {
            #pragma unroll
            for (int jt = 0; jt < JT; jt++)
                out[ng * COUT + jt * 64 + j] = fmaxf(acc[k][jt], 0.f);
        }
    }
}

// pooled sum over 1024 boundary rows of x3b (compact 1024x256)
__global__ void pool_kernel(const float* __restrict__ x3b, float* __restrict__ pooled) {
    int j = threadIdx.x;
    int r0 = blockIdx.x * 32;
    float s = 0.f;
    for (int r = 0; r < 32; r++) s += x3b[(r0 + r) * 256 + j];
    atomicAdd(&pooled[j], s);
}

// head: pooled/1024 -> fc(relu) -> out(12) + bmean broadcast
__global__ void head_kernel(const float* __restrict__ pooled_sum, const float* __restrict__ bmean,
                            const float* __restrict__ Wd, const float* __restrict__ bd,
                            const float* __restrict__ Wo, const float* __restrict__ bo,
                            float* __restrict__ out) {
    __shared__ float p_l[256], h_l[256];
    int tid = threadIdx.x;
    p_l[tid] = pooled_sum[tid] * (1.0f / NB);
    __syncthreads();
    float acc = bd[tid];
    for (int c = 0; c < 256; c++) acc = fmaf(p_l[c], Wd[c * 256 + tid], acc);
    h_l[tid] = fmaxf(acc, 0.f);
    __syncthreads();
    if (tid < 12) {
        float o = bo[tid];
        for (int c = 0; c < 256; c++) o = fmaf(h_l[c], Wo[c * 12 + tid], o);
        out[tid] = o + bmean[tid % 3];
    }
}

extern "C" void kernel_launch(void* const* d_in, const int* in_sizes, int n_in,
                              void* d_out, int out_size, void* d_ws, size_t ws_size,
                              hipStream_t stream) {
    const float* vs    = (const float*)d_in[0];
    const int2*  edges = (const int2*)d_in[1];
    const int*   bidx  = (const int*)d_in[2];
    const float* Ws0 = (const float*)d_in[4];
    const float* Wn0 = (const float*)d_in[5];
    const float* b0  = (const float*)d_in[6];
    const float* Ws1 = (const float*)d_in[7];
    const float* Wn1 = (const float*)d_in[8];
    const float* b1  = (const float*)d_in[9];
    const float* Ws2 = (const float*)d_in[10];
    const float* Wn2 = (const float*)d_in[11];
    const float* b2  = (const float*)d_in[12];
    const float* Wd  = (const float*)d_in[13];
    const float* bd  = (const float*)d_in[14];
    const float* Wo  = (const float*)d_in[15];
    const float* bo  = (const float*)d_in[16];

    float* ws = (float*)d_ws;
    float* x1c    = ws + OFF_X1C;
    float* x2c    = ws + OFF_X2C;
    float* x3b    = ws + OFF_X3B;
    float* agg0c  = ws + OFF_AGG0C;
    float* agg1c  = ws + OFF_AGG1C;
    float* agg2c  = ws + OFF_AGG2C;
    float* pooled = ws + OFF_POOL;
    int*   cnt    = (int*)(ws + OFF_CNT);
    int*   degF2  = (int*)(ws + OFF_DEGF2);
    int*   degF1  = (int*)(ws + OFF_DEGF1);
    int*   degB   = (int*)(ws + OFF_DEGB);
    int*   mF1    = (int*)(ws + OFF_MF1);
    int*   mF2    = (int*)(ws + OFF_MF2);
    int*   slotB  = (int*)(ws + OFF_SLOTB);
    int*   slotF1 = (int*)(ws + OFF_SLOTF1);
    int*   slotF2 = (int*)(ws + OFF_SLOTF2);
    int*   listF1 = (int*)(ws + OFF_LISTF1);
    int*   listF2 = (int*)(ws + OFF_LISTF2);
    int*   adj0   = (int*)(ws + OFF_ADJ0);
    int*   adjF1  = (int*)(ws + OFF_ADJF1);
    int*   adjB   = (int*)(ws + OFF_ADJB);
    int*   idxx2  = (int*)(ws + OFF_IDXX2);
    int*   idxa2  = (int*)(ws + OFF_IDXA2);
    int*   f1f2   = (int*)(ws + OFF_F1F2);
    float* bmean  = ws + OFF_BMEAN;
    float* outp   = (float*)d_out;

    const int EB = (N_EDGES + 255) / 256;
    const int NBLK = (N_NODES + 255) / 256;

    hipMemsetAsync(ws + OFF_POOL, 0, ZERO_BYTES, stream);      // cnt, deg*, marks, pool
    hipMemsetAsync(ws + OFF_SLOTB, 0xFF, FF_BYTES, stream);    // slotB = -1

    bmean_kernel<<<1, 256, 0, stream>>>(vs, bidx, bmean);

    // frontier construction: mark (plain stores) -> compact (block-aggregated alloc)
    mark_b_kernel<<<(NB + 255) / 256, 256, 0, stream>>>(bidx, slotB);
    scan_mark_kernel<<<EB, 256, 0, stream>>>(edges, slotB, mF1);
    compact_kernel<<<NBLK, 256, 0, stream>>>(mF1, slotB, slotF1, listF1,
                                             cnt + CNT_F1, CAP_F1, nullptr);
    scan_mark_kernel<<<EB, 256, 0, stream>>>(edges, slotF1, mF2);
    compact_kernel<<<NBLK, 256, 0, stream>>>(mF2, slotF1, slotF2, listF2,
                                             cnt + CNT_F2, CAP_F2, f1f2);
    build_adj_kernel<<<EB, 256, 0, stream>>>(edges, slotB, slotF1, slotF2,
                                             degF2, adj0, degF1, adjF1, degB, adjB);
    conv2_idx_kernel<<<(NB + 255) / 256, 256, 0, stream>>>(bidx, slotB, slotF1, idxx2, idxa2);

    // layer 0 on F2 (gather, no fp atomics)
    gather0_kernel<<<CAP_F2 / 256, 256, 0, stream>>>(vs, adj0, degF2, cnt, agg0c);
    conv0c_kernel<<<CAP_F2 / 4, 256, 0, stream>>>(vs, listF2, agg0c, Ws0, Wn0, b0, cnt, x1c);

    // layer 1 on F1
    gather1_kernel<<<CAP_F1 / 4, 256, 0, stream>>>(x1c, adjF1, degF1, cnt, agg1c);
    convN_kernel<64, 128><<<CAP_F1 / 64, 256, 0, stream>>>(
        x1c, agg1c, Ws1, Wn1, b1, x2c, f1f2, nullptr, CAP_F1, cnt + CNT_F1);

    // layer 2 on boundary
    gather2_kernel<<<NB / 4, 256, 0, stream>>>(x2c, adjB, degB, agg2c);
    convN_kernel<128, 256><<<NB / 64, 256, 0, stream>>>(
        x2c, agg2c, Ws2, Wn2, b2, x3b, idxx2, idxa2, NB, nullptr);

    // head
    pool_kernel<<<32, 256, 0, stream>>>(x3b, pooled);
    head_kernel<<<1, 256, 0, stream>>>(pooled, bmean, Wd, bd, Wo, bo, outp);
}

// Round 12
// 258.748 us; speedup vs baseline: 1.7458x; 1.0463x over previous
//
#include <hip/hip_runtime.h>

#define N_NODES 100000
#define N_EDGES 300000
#define NB 1024

#define CAP_F1 16384        // F1 = boundary ∪ N(boundary), expected ~7.2k
#define CAP_F2 65536        // F2 = F1 ∪ N(F1), expected ~41k
#define K_ADJ  64           // per-slot adjacency cap (deg ~ Poisson(6))

// padded counter indices (64B apart)
#define CNT_F1 0
#define CNT_F2 16

// ---------------- workspace layout (float offsets) ----------------
#define OFF_X1C     0u          // CAP_F2*64  = 4,194,304
#define OFF_X2C     4194304u    // CAP_F1*128 = 2,097,152
#define OFF_X3B     6291456u    // 1024*256   = 262,144
#define OFF_AGG0C   6553600u    // CAP_F2*4   = 262,144   (fully written by gather0)
#define OFF_AGG1C   6815744u    // CAP_F1*64  = 1,048,576 (fully written by gather1)
#define OFF_AGG2C   7864320u    // 1024*128   = 131,072   (fully written by gather2)
// ---- zero region ----
#define OFF_POOL    7995392u    // 256
#define OFF_CNT     7995648u    // 64
#define OFF_DEGF2   7995712u    // 65,536
#define OFF_DEGF1   8061248u    // 16,384
#define OFF_DEGB    8077632u    // 1,024
#define OFF_MF1     8078656u    // 100,000
#define OFF_MF2     8178656u    // 100,000
#define ZERO_END    8278656u
#define ZERO_BYTES  ((ZERO_END - OFF_POOL) * 4u)
// ---- 0xFF region ----
#define OFF_SLOTB   8278656u    // 100,000
#define FF_BYTES    (100000u * 4u)
// ---- no-init region (fully written before read) ----
#define OFF_SLOTF1  8378656u    // 100,000 (compactF1 writes all)
#define OFF_SLOTF2  8478656u    // 100,000 (compactF2 writes all)
#define OFF_LISTF1  8578656u    // 16,384
#define OFF_LISTF2  8595040u    // 65,536
#define OFF_ADJ0    8660576u    // CAP_F2*64 = 4,194,304 (node ids)
#define OFF_ADJF1   12854880u   // CAP_F1*64 = 1,048,576 (F2 slots)
#define OFF_ADJB    13903456u   // 1024*64   = 65,536    (F1 slots)
#define OFF_IDXX2   13968992u   // 1024
#define OFF_IDXA2   13970016u   // 1024
#define OFF_F1F2    13971040u   // 16,384 (F1 slot -> F2 slot)
#define OFF_BMEAN   13987424u   // 3

// boundary mean of vs -> bmean[3]
__global__ void bmean_kernel(const float* __restrict__ vs, const int* __restrict__ bidx,
                             float* __restrict__ bmean) {
    int tid = threadIdx.x;
    float s0 = 0.f, s1 = 0.f, s2 = 0.f;
    for (int i = tid; i < NB; i += 256) {
        int n = bidx[i];
        s0 += vs[n * 3 + 0];
        s1 += vs[n * 3 + 1];
        s2 += vs[n * 3 + 2];
    }
    for (int off = 32; off > 0; off >>= 1) {
        s0 += __shfl_down(s0, off);
        s1 += __shfl_down(s1, off);
        s2 += __shfl_down(s2, off);
    }
    __shared__ float red[4][3];
    int wave = tid >> 6;
    if ((tid & 63) == 0) { red[wave][0] = s0; red[wave][1] = s1; red[wave][2] = s2; }
    __syncthreads();
    if (tid == 0) {
        float t0 = 0, t1 = 0, t2 = 0;
        for (int w = 0; w < 4; w++) { t0 += red[w][0]; t1 += red[w][1]; t2 += red[w][2]; }
        bmean[0] = t0 / NB; bmean[1] = t1 / NB; bmean[2] = t2 / NB;
    }
}

// A: slotB map (plain stores; duplicates -> any winner, consistent everywhere)
__global__ void mark_b_kernel(const int* __restrict__ bidx, int* __restrict__ slotB) {
    int i = blockIdx.x * 256 + threadIdx.x;
    if (i < NB) slotB[bidx[i]] = i;
}

// B: mark neighbors of {src set}: mark[x] = 1 if other endpoint in set.
// Idempotent plain stores — no atomics, no counter.
__global__ void scan_mark_kernel(const int2* __restrict__ edges, const int* __restrict__ srcSlot,
                                 int* __restrict__ mark) {
    int e = blockIdx.x * 256 + threadIdx.x;
    if (e >= N_EDGES) return;
    int2 ed = edges[e];
    if (srcSlot[ed.y] >= 0) mark[ed.x] = 1;
    if (srcSlot[ed.x] >= 0) mark[ed.y] = 1;
}

// C: dense compact over all nodes: want = mark[i] || aux[i]>=0.
// Block-aggregated allocation: ONE counter atomic per block (391 total).
// Writes slot[i] for EVERY node (-1 if not wanted) -> no FF-init needed.
// If f1map!=nullptr: for nodes with aux[i]>=0 (F1 members), f1map[aux[i]] = slot.
__global__ __launch_bounds__(256) void compact_kernel(
        const int* __restrict__ mark, const int* __restrict__ aux,
        int* __restrict__ slot, int* __restrict__ list,
        int* __restrict__ cnt, int cap, int* __restrict__ f1map) {
    int i = blockIdx.x * 256 + threadIdx.x;
    int auxv = -1;
    bool want = false;
    if (i < N_NODES) {
        auxv = aux[i];
        want = (mark[i] != 0) || (auxv >= 0);
    }
    int wave = threadIdx.x >> 6, lane = threadIdx.x & 63;
    unsigned long long m = __ballot(want);
    int rank = __popcll(m & ((1ull << lane) - 1));
    __shared__ int s_w[4];
    __shared__ int s_base;
    if (lane == 0) s_w[wave] = __popcll(m);
    __syncthreads();
    if (threadIdx.x == 0) {
        int s = 0;
        #pragma unroll
        for (int w = 0; w < 4; w++) { int v = s_w[w]; s_w[w] = s; s += v; }
        s_base = s ? atomicAdd(cnt, s) : 0;
    }
    __syncthreads();
    if (i < N_NODES) {
        int p = -1;
        if (want) {
            p = s_base + s_w[wave] + rank;
            if (p < cap) list[p] = i; else p = -1;   // overflow -> excluded
        }
        slot[i] = p;
        if (f1map && auxv >= 0) f1map[auxv] = p;     // F1 slot -> F2 slot
    }
}

__device__ __forceinline__ void adj_append(int* __restrict__ deg, int* __restrict__ adj,
                                           int slot, int src) {
    int pos = atomicAdd(&deg[slot], 1);
    if (pos < K_ADJ) adj[slot * K_ADJ + pos] = src;
}

// D: one edge pass -> per-slot adjacency lists (distributed atomics — proven cheap)
__global__ void build_adj_kernel(const int2* __restrict__ edges,
                                 const int* __restrict__ slotB, const int* __restrict__ slotF1,
                                 const int* __restrict__ slotF2,
                                 int* __restrict__ degF2, int* __restrict__ adj0,
                                 int* __restrict__ degF1, int* __restrict__ adjF1,
                                 int* __restrict__ degB, int* __restrict__ adjB) {
    int e = blockIdx.x * 256 + threadIdx.x;
    if (e >= N_EDGES) return;
    int2 ed = edges[e];
    int x = ed.x, y = ed.y;
    int sxB = slotB[x], syB = slotB[y];
    int sxF1 = slotF1[x], syF1 = slotF1[y];
    int sxF2 = slotF2[x], syF2 = slotF2[y];
    if (syF2 >= 0) adj_append(degF2, adj0, syF2, x);     // agg0 sources: raw node ids
    if (sxF2 >= 0) adj_append(degF2, adj0, sxF2, y);
    if (syF1 >= 0) adj_append(degF1, adjF1, syF1, sxF2); // agg1 sources: F2 slots (N(F1) ⊆ F2)
    if (sxF1 >= 0) adj_append(degF1, adjF1, sxF1, syF2);
    if (syB >= 0)  adj_append(degB, adjB, syB, sxF1);    // agg2 sources: F1 slots (N(B) ⊆ F1)
    if (sxB >= 0)  adj_append(degB, adjB, sxB, syF1);
}

// E: gather index arrays for conv2 (per boundary position, duplicates handled)
__global__ void conv2_idx_kernel(const int* __restrict__ bidx, const int* __restrict__ slotB,
                                 const int* __restrict__ slotF1,
                                 int* __restrict__ idxx, int* __restrict__ idxa) {
    int i = blockIdx.x * 256 + threadIdx.x;
    if (i >= NB) return;
    int n = bidx[i];
    idxx[i] = slotF1[n];
    idxa[i] = slotB[n];
}

// gather agg0 (3ch) per F2 slot: thread per slot
__global__ void gather0_kernel(const float* __restrict__ vs, const int* __restrict__ adj0,
                               const int* __restrict__ degF2, const int* __restrict__ cnt,
                               float* __restrict__ agg0c) {
    int s = blockIdx.x * 256 + threadIdx.x;
    int n = min(cnt[CNT_F2], CAP_F2);
    if (s >= n) return;
    int deg = min(degF2[s], K_ADJ);
    float a0 = 0.f, a1 = 0.f, a2 = 0.f;
    for (int d = 0; d < deg; d++) {
        int src = adj0[s * K_ADJ + d];
        a0 += vs[src * 3 + 0];
        a1 += vs[src * 3 + 1];
        a2 += vs[src * 3 + 2];
    }
    agg0c[s * 4 + 0] = a0; agg0c[s * 4 + 1] = a1; agg0c[s * 4 + 2] = a2;
}

// conv0 on compact F2 rows: 3 -> 64, relu. block = 4 slots x 64 couts
__global__ void conv0c_kernel(const float* __restrict__ vs, const int* __restrict__ listF2,
                              const float* __restrict__ agg0c,
                              const float* __restrict__ Ws, const float* __restrict__ Wn,
                              const float* __restrict__ b, const int* __restrict__ cnt,
                              float* __restrict__ x1c) {
    int nF2 = min(cnt[CNT_F2], CAP_F2);
    if ((int)blockIdx.x * 4 >= nF2) return;
    __shared__ float ws_l[192], wn_l[192], b_l[64];
    int tid = threadIdx.x;
    if (tid < 192) { ws_l[tid] = Ws[tid]; wn_l[tid] = Wn[tid]; }
    if (tid < 64) b_l[tid] = b[tid];
    __syncthreads();
    int g = blockIdx.x * 4 + (tid >> 6);
    int j = tid & 63;
    if (g >= nF2) return;
    int n = listF2[g];
    float x0 = vs[n * 3 + 0], x1v = vs[n * 3 + 1], x2v = vs[n * 3 + 2];
    float a0 = agg0c[g * 4 + 0], a1 = agg0c[g * 4 + 1], a2 = agg0c[g * 4 + 2];
    float acc = b_l[j];
    acc = fmaf(x0, ws_l[0 * 64 + j], acc);
    acc = fmaf(x1v, ws_l[1 * 64 + j], acc);
    acc = fmaf(x2v, ws_l[2 * 64 + j], acc);
    acc = fmaf(a0, wn_l[0 * 64 + j], acc);
    acc = fmaf(a1, wn_l[1 * 64 + j], acc);
    acc = fmaf(a2, wn_l[2 * 64 + j], acc);
    x1c[g * 64 + j] = fmaxf(acc, 0.f);
}

// gather agg1 (64ch) per F1 slot: wave per slot, lane = channel
__global__ __launch_bounds__(256) void gather1_kernel(const float* __restrict__ x1c,
                                                      const int* __restrict__ adjF1,
                                                      const int* __restrict__ degF1,
                                                      const int* __restrict__ cnt,
                                                      float* __restrict__ agg1c) {
    int wslot = blockIdx.x * 4 + (threadIdx.x >> 6);
    int lane = threadIdx.x & 63;
    int n = min(cnt[CNT_F1], CAP_F1);
    if (wslot >= n) return;
    int deg = min(degF1[wslot], K_ADJ);
    float acc = 0.f;
    for (int d = 0; d < deg; d++) {
        int src = adjF1[wslot * K_ADJ + d];
        if (src >= 0) acc += x1c[src * 64 + lane];
    }
    agg1c[wslot * 64 + lane] = acc;
}

// gather agg2 (128ch) per boundary slot: wave per slot, 2 channel halves
__global__ __launch_bounds__(256) void gather2_kernel(const float* __restrict__ x2c,
                                                      const int* __restrict__ adjB,
                                                      const int* __restrict__ degB,
                                                      float* __restrict__ agg2c) {
    int wslot = blockIdx.x * 4 + (threadIdx.x >> 6);   // < 1024
    int lane = threadIdx.x & 63;
    int deg = min(degB[wslot], K_ADJ);
    float a0 = 0.f, a1 = 0.f;
    for (int d = 0; d < deg; d++) {
        int src = adjB[wslot * K_ADJ + d];
        if (src >= 0) {
            a0 += x2c[src * 128 + lane];
            a1 += x2c[src * 128 + 64 + lane];
        }
    }
    agg2c[wslot * 128 + lane] = a0;
    agg2c[wslot * 128 + 64 + lane] = a1;
}

// tiled conv: CIN -> COUT, relu. Grid: (row tiles, COUT/64).
// 256 threads = 64 cout-lanes x 4 row-groups; each thread: ROWS/4 rows x 1 cout.
// LDS tile ROWS x CIN x 2 (float4-staged). Wave LDS reads are broadcast (no conflict).
template <int CIN, int COUT, int ROWS>
__global__ __launch_bounds__(256) void convT_kernel(
    const float* __restrict__ x, const float* __restrict__ agg,
    const float* __restrict__ Ws, const float* __restrict__ Wn,
    const float* __restrict__ b, float* __restrict__ out,
    const int* __restrict__ idxx, const int* __restrict__ idxa,
    int nrows_max, const int* __restrict__ nrows_dev) {
    const int RPT = ROWS / 4;
    const int C4 = CIN / 4;
    __shared__ float xs[ROWS * CIN];
    __shared__ float as[ROWS * CIN];
    int nrows = nrows_max;
    if (nrows_dev) { int nd = nrows_dev[0]; nrows = nd < nrows ? nd : nrows; }
    int gbase = blockIdx.x * ROWS;
    if (gbase >= nrows) return;
    int tid = threadIdx.x;
    int cb = blockIdx.y * 64;
    for (int i = tid; i < ROWS * C4; i += 256) {
        int nl = i / C4, c4 = i % C4;
        int ng = gbase + nl;
        float4 xv = make_float4(0.f, 0.f, 0.f, 0.f);
        float4 av = xv;
        if (ng < nrows) {
            int rowx = idxx ? idxx[ng] : ng;
            int rowa = idxa ? idxa[ng] : ng;
            xv = ((const float4*)x)[rowx * C4 + c4];
            av = ((const float4*)agg)[rowa * C4 + c4];
        }
        ((float4*)xs)[i] = xv;
        ((float4*)as)[i] = av;
    }
    __syncthreads();
    int j = tid & 63, g = tid >> 6;
    float acc[RPT];
    float bv = b[cb + j];
    #pragma unroll
    for (int k = 0; k < RPT; k++) acc[k] = bv;
    #pragma unroll 4
    for (int c = 0; c < CIN; c++) {
        float wsv = Ws[c * COUT + cb + j];
        float wnv = Wn[c * COUT + cb + j];
        #pragma unroll
        for (int k = 0; k < RPT; k++) {
            float xv = xs[(g * RPT + k) * CIN + c];
            float av = as[(g * RPT + k) * CIN + c];
            acc[k] = fmaf(xv, wsv, fmaf(av, wnv, acc[k]));
        }
    }
    #pragma unroll
    for (int k = 0; k < RPT; k++) {
        int ng = gbase + g * RPT + k;
        if (ng < nrows) out[ng * COUT + cb + j] = fmaxf(acc[k], 0.f);
    }
}

// pooled sum over 1024 boundary rows of x3b (compact 1024x256)
__global__ void pool_kernel(const float* __restrict__ x3b, float* __restrict__ pooled) {
    int j = threadIdx.x;
    int r0 = blockIdx.x * 32;
    float s = 0.f;
    for (int r = 0; r < 32; r++) s += x3b[(r0 + r) * 256 + j];
    atomicAdd(&pooled[j], s);
}

// head: pooled/1024 -> fc(relu) -> out(12) + bmean broadcast
__global__ void head_kernel(const float* __restrict__ pooled_sum, const float* __restrict__ bmean,
                            const float* __restrict__ Wd, const float* __restrict__ bd,
                            const float* __restrict__ Wo, const float* __restrict__ bo,
                            float* __restrict__ out) {
    __shared__ float p_l[256], h_l[256];
    int tid = threadIdx.x;
    p_l[tid] = pooled_sum[tid] * (1.0f / NB);
    __syncthreads();
    float acc = bd[tid];
    for (int c = 0; c < 256; c++) acc = fmaf(p_l[c], Wd[c * 256 + tid], acc);
    h_l[tid] = fmaxf(acc, 0.f);
    __syncthreads();
    if (tid < 12) {
        float o = bo[tid];
        for (int c = 0; c < 256; c++) o = fmaf(h_l[c], Wo[c * 12 + tid], o);
        out[tid] = o + bmean[tid % 3];
    }
}

extern "C" void kernel_launch(void* const* d_in, const int* in_sizes, int n_in,
                              void* d_out, int out_size, void* d_ws, size_t ws_size,
                              hipStream_t stream) {
    const float* vs    = (const float*)d_in[0];
    const int2*  edges = (const int2*)d_in[1];
    const int*   bidx  = (const int*)d_in[2];
    const float* Ws0 = (const float*)d_in[4];
    const float* Wn0 = (const float*)d_in[5];
    const float* b0  = (const float*)d_in[6];
    const float* Ws1 = (const float*)d_in[7];
    const float* Wn1 = (const float*)d_in[8];
    const float* b1  = (const float*)d_in[9];
    const float* Ws2 = (const float*)d_in[10];
    const float* Wn2 = (const float*)d_in[11];
    const float* b2  = (const float*)d_in[12];
    const float* Wd  = (const float*)d_in[13];
    const float* bd  = (const float*)d_in[14];
    const float* Wo  = (const float*)d_in[15];
    const float* bo  = (const float*)d_in[16];

    float* ws = (float*)d_ws;
    float* x1c    = ws + OFF_X1C;
    float* x2c    = ws + OFF_X2C;
    float* x3b    = ws + OFF_X3B;
    float* agg0c  = ws + OFF_AGG0C;
    float* agg1c  = ws + OFF_AGG1C;
    float* agg2c  = ws + OFF_AGG2C;
    float* pooled = ws + OFF_POOL;
    int*   cnt    = (int*)(ws + OFF_CNT);
    int*   degF2  = (int*)(ws + OFF_DEGF2);
    int*   degF1  = (int*)(ws + OFF_DEGF1);
    int*   degB   = (int*)(ws + OFF_DEGB);
    int*   mF1    = (int*)(ws + OFF_MF1);
    int*   mF2    = (int*)(ws + OFF_MF2);
    int*   slotB  = (int*)(ws + OFF_SLOTB);
    int*   slotF1 = (int*)(ws + OFF_SLOTF1);
    int*   slotF2 = (int*)(ws + OFF_SLOTF2);
    int*   listF1 = (int*)(ws + OFF_LISTF1);
    int*   listF2 = (int*)(ws + OFF_LISTF2);
    int*   adj0   = (int*)(ws + OFF_ADJ0);
    int*   adjF1  = (int*)(ws + OFF_ADJF1);
    int*   adjB   = (int*)(ws + OFF_ADJB);
    int*   idxx2  = (int*)(ws + OFF_IDXX2);
    int*   idxa2  = (int*)(ws + OFF_IDXA2);
    int*   f1f2   = (int*)(ws + OFF_F1F2);
    float* bmean  = ws + OFF_BMEAN;
    float* outp   = (float*)d_out;

    const int EB = (N_EDGES + 255) / 256;
    const int NBLK = (N_NODES + 255) / 256;

    hipMemsetAsync(ws + OFF_POOL, 0, ZERO_BYTES, stream);      // cnt, deg*, marks, pool
    hipMemsetAsync(ws + OFF_SLOTB, 0xFF, FF_BYTES, stream);    // slotB = -1

    bmean_kernel<<<1, 256, 0, stream>>>(vs, bidx, bmean);

    // frontier construction: mark (plain stores) -> compact (block-aggregated alloc)
    mark_b_kernel<<<(NB + 255) / 256, 256, 0, stream>>>(bidx, slotB);
    scan_mark_kernel<<<EB, 256, 0, stream>>>(edges, slotB, mF1);
    compact_kernel<<<NBLK, 256, 0, stream>>>(mF1, slotB, slotF1, listF1,
                                             cnt + CNT_F1, CAP_F1, nullptr);
    scan_mark_kernel<<<EB, 256, 0, stream>>>(edges, slotF1, mF2);
    compact_kernel<<<NBLK, 256, 0, stream>>>(mF2, slotF1, slotF2, listF2,
                                             cnt + CNT_F2, CAP_F2, f1f2);
    build_adj_kernel<<<EB, 256, 0, stream>>>(edges, slotB, slotF1, slotF2,
                                             degF2, adj0, degF1, adjF1, degB, adjB);
    conv2_idx_kernel<<<(NB + 255) / 256, 256, 0, stream>>>(bidx, slotB, slotF1, idxx2, idxa2);

    // layer 0 on F2 (gather, no fp atomics)
    gather0_kernel<<<CAP_F2 / 256, 256, 0, stream>>>(vs, adj0, degF2, cnt, agg0c);
    conv0c_kernel<<<CAP_F2 / 4, 256, 0, stream>>>(vs, listF2, agg0c, Ws0, Wn0, b0, cnt, x1c);

    // layer 1 on F1: 32-row tiles x 2 cout-tiles
    gather1_kernel<<<CAP_F1 / 4, 256, 0, stream>>>(x1c, adjF1, degF1, cnt, agg1c);
    convT_kernel<64, 128, 32><<<dim3(CAP_F1 / 32, 2), 256, 0, stream>>>(
        x1c, agg1c, Ws1, Wn1, b1, x2c, f1f2, nullptr, CAP_F1, cnt + CNT_F1);

    // layer 2 on boundary: 16-row tiles x 4 cout-tiles = 256 blocks
    gather2_kernel<<<NB / 4, 256, 0, stream>>>(x2c, adjB, degB, agg2c);
    convT_kernel<128, 256, 16><<<dim3(NB / 16, 4), 256, 0, stream>>>(
        x2c, agg2c, Ws2, Wn2, b2, x3b, idxx2, idxa2, NB, nullptr);

    // head
    pool_kernel<<<32, 256, 0, stream>>>(x3b, pooled);
    head_kernel<<<1, 256, 0, stream>>>(pooled, bmean, Wd, bd, Wo, bo, outp);
}

// Round 13
// 232.938 us; speedup vs baseline: 1.9393x; 1.1108x over previous
//
#include <hip/hip_runtime.h>

#define N_NODES 100000
#define N_EDGES 300000
#define NB 1024

#define CAP_F1 16384        // F1 = boundary ∪ N(boundary), expected ~7.2k
#define CAP_F2 65536        // F2 = F1 ∪ N(F1), expected ~41k
#define K_ADJ  64           // per-slot adjacency cap (deg ~ Poisson(6))

// padded counter indices (64B apart)
#define CNT_F1 0
#define CNT_F2 16

// ---------------- workspace layout (float offsets) ----------------
#define OFF_X1C     0u          // CAP_F2*64  = 4,194,304
#define OFF_X2C     4194304u    // CAP_F1*128 = 2,097,152
#define OFF_X3B     6291456u    // 1024*256   = 262,144
#define OFF_AGG0C   6553600u    // CAP_F2*4   = 262,144   (fully written by gather0)
#define OFF_AGG1C   6815744u    // CAP_F1*64  = 1,048,576 (fully written by gather1)
#define OFF_AGG2C   7864320u    // 1024*128   = 131,072   (fully written by gather2)
// ---- zero region ----
#define OFF_POOL    7995392u    // 256
#define OFF_CNT     7995648u    // 64
#define OFF_DEGF2   7995712u    // 65,536
#define OFF_DEGF1   8061248u    // 16,384
#define OFF_DEGB    8077632u    // 1,024
#define OFF_MF1     8078656u    // 100,000
#define OFF_MF2     8178656u    // 100,000
#define ZERO_END    8278656u
#define ZERO_BYTES  ((ZERO_END - OFF_POOL) * 4u)
// ---- 0xFF region ----
#define OFF_SLOTB   8278656u    // 100,000
#define FF_BYTES    (100000u * 4u)
// ---- no-init region (fully written before read) ----
#define OFF_SLOTF1  8378656u    // 100,000 (compactF1 writes all)
#define OFF_SLOTF2  8478656u    // 100,000 (compactF2 writes all)
#define OFF_LISTF1  8578656u    // 16,384
#define OFF_LISTF2  8595040u    // 65,536
#define OFF_ADJ0    8660576u    // CAP_F2*64 = 4,194,304 (node ids)
#define OFF_ADJF1   12854880u   // CAP_F1*64 = 1,048,576 (F2 slots)
#define OFF_ADJB    13903456u   // 1024*64   = 65,536    (F1 slots)
#define OFF_IDXX2   13968992u   // 1024
#define OFF_IDXA2   13970016u   // 1024
#define OFF_F1F2    13971040u   // 16,384 (F1 slot -> F2 slot)
#define OFF_BMEAN   13987424u   // 3

// boundary mean of vs -> bmean[3]
__global__ void bmean_kernel(const float* __restrict__ vs, const int* __restrict__ bidx,
                             float* __restrict__ bmean) {
    int tid = threadIdx.x;
    float s0 = 0.f, s1 = 0.f, s2 = 0.f;
    for (int i = tid; i < NB; i += 256) {
        int n = bidx[i];
        s0 += vs[n * 3 + 0];
        s1 += vs[n * 3 + 1];
        s2 += vs[n * 3 + 2];
    }
    for (int off = 32; off > 0; off >>= 1) {
        s0 += __shfl_down(s0, off);
        s1 += __shfl_down(s1, off);
        s2 += __shfl_down(s2, off);
    }
    __shared__ float red[4][3];
    int wave = tid >> 6;
    if ((tid & 63) == 0) { red[wave][0] = s0; red[wave][1] = s1; red[wave][2] = s2; }
    __syncthreads();
    if (tid == 0) {
        float t0 = 0, t1 = 0, t2 = 0;
        for (int w = 0; w < 4; w++) { t0 += red[w][0]; t1 += red[w][1]; t2 += red[w][2]; }
        bmean[0] = t0 / NB; bmean[1] = t1 / NB; bmean[2] = t2 / NB;
    }
}

// A: slotB map (plain stores; duplicates -> any winner, consistent everywhere)
__global__ void mark_b_kernel(const int* __restrict__ bidx, int* __restrict__ slotB) {
    int i = blockIdx.x * 256 + threadIdx.x;
    if (i < NB) slotB[bidx[i]] = i;
}

// B: mark neighbors of {src set}: mark[x] = 1 if other endpoint in set.
// Idempotent plain stores — no atomics, no counter.
__global__ void scan_mark_kernel(const int2* __restrict__ edges, const int* __restrict__ srcSlot,
                                 int* __restrict__ mark) {
    int e = blockIdx.x * 256 + threadIdx.x;
    if (e >= N_EDGES) return;
    int2 ed = edges[e];
    if (srcSlot[ed.y] >= 0) mark[ed.x] = 1;
    if (srcSlot[ed.x] >= 0) mark[ed.y] = 1;
}

// C: dense compact over all nodes: want = mark[i] || aux[i]>=0.
// Block-aggregated allocation: ONE counter atomic per block (391 total).
// Writes slot[i] for EVERY node (-1 if not wanted) -> no FF-init needed.
// If f1map!=nullptr: for nodes with aux[i]>=0 (F1 members), f1map[aux[i]] = slot.
__global__ __launch_bounds__(256) void compact_kernel(
        const int* __restrict__ mark, const int* __restrict__ aux,
        int* __restrict__ slot, int* __restrict__ list,
        int* __restrict__ cnt, int cap, int* __restrict__ f1map) {
    int i = blockIdx.x * 256 + threadIdx.x;
    int auxv = -1;
    bool want = false;
    if (i < N_NODES) {
        auxv = aux[i];
        want = (mark[i] != 0) || (auxv >= 0);
    }
    int wave = threadIdx.x >> 6, lane = threadIdx.x & 63;
    unsigned long long m = __ballot(want);
    int rank = __popcll(m & ((1ull << lane) - 1));
    __shared__ int s_w[4];
    __shared__ int s_base;
    if (lane == 0) s_w[wave] = __popcll(m);
    __syncthreads();
    if (threadIdx.x == 0) {
        int s = 0;
        #pragma unroll
        for (int w = 0; w < 4; w++) { int v = s_w[w]; s_w[w] = s; s += v; }
        s_base = s ? atomicAdd(cnt, s) : 0;
    }
    __syncthreads();
    if (i < N_NODES) {
        int p = -1;
        if (want) {
            p = s_base + s_w[wave] + rank;
            if (p < cap) list[p] = i; else p = -1;   // overflow -> excluded
        }
        slot[i] = p;
        if (f1map && auxv >= 0) f1map[auxv] = p;     // F1 slot -> F2 slot
    }
}

__device__ __forceinline__ void adj_append(int* __restrict__ deg, int* __restrict__ adj,
                                           int slot, int src) {
    int pos = atomicAdd(&deg[slot], 1);
    if (pos < K_ADJ) adj[slot * K_ADJ + pos] = src;
}

// D: one edge pass -> per-slot adjacency lists (distributed atomics — proven cheap)
__global__ void build_adj_kernel(const int2* __restrict__ edges,
                                 const int* __restrict__ slotB, const int* __restrict__ slotF1,
                                 const int* __restrict__ slotF2,
                                 int* __restrict__ degF2, int* __restrict__ adj0,
                                 int* __restrict__ degF1, int* __restrict__ adjF1,
                                 int* __restrict__ degB, int* __restrict__ adjB) {
    int e = blockIdx.x * 256 + threadIdx.x;
    if (e >= N_EDGES) return;
    int2 ed = edges[e];
    int x = ed.x, y = ed.y;
    int sxB = slotB[x], syB = slotB[y];
    int sxF1 = slotF1[x], syF1 = slotF1[y];
    int sxF2 = slotF2[x], syF2 = slotF2[y];
    if (syF2 >= 0) adj_append(degF2, adj0, syF2, x);     // agg0 sources: raw node ids
    if (sxF2 >= 0) adj_append(degF2, adj0, sxF2, y);
    if (syF1 >= 0) adj_append(degF1, adjF1, syF1, sxF2); // agg1 sources: F2 slots (N(F1) ⊆ F2)
    if (sxF1 >= 0) adj_append(degF1, adjF1, sxF1, syF2);
    if (syB >= 0)  adj_append(degB, adjB, syB, sxF1);    // agg2 sources: F1 slots (N(B) ⊆ F1)
    if (sxB >= 0)  adj_append(degB, adjB, sxB, syF1);
}

// E: gather index arrays for conv2 (per boundary position, duplicates handled)
__global__ void conv2_idx_kernel(const int* __restrict__ bidx, const int* __restrict__ slotB,
                                 const int* __restrict__ slotF1,
                                 int* __restrict__ idxx, int* __restrict__ idxa) {
    int i = blockIdx.x * 256 + threadIdx.x;
    if (i >= NB) return;
    int n = bidx[i];
    idxx[i] = slotF1[n];
    idxa[i] = slotB[n];
}

// gather agg0 (3ch) per F2 slot: thread per slot
__global__ void gather0_kernel(const float* __restrict__ vs, const int* __restrict__ adj0,
                               const int* __restrict__ degF2, const int* __restrict__ cnt,
                               float* __restrict__ agg0c) {
    int s = blockIdx.x * 256 + threadIdx.x;
    int n = min(cnt[CNT_F2], CAP_F2);
    if (s >= n) return;
    int deg = min(degF2[s], K_ADJ);
    float a0 = 0.f, a1 = 0.f, a2 = 0.f;
    for (int d = 0; d < deg; d++) {
        int src = adj0[s * K_ADJ + d];
        a0 += vs[src * 3 + 0];
        a1 += vs[src * 3 + 1];
        a2 += vs[src * 3 + 2];
    }
    agg0c[s * 4 + 0] = a0; agg0c[s * 4 + 1] = a1; agg0c[s * 4 + 2] = a2;
}

// conv0 on compact F2 rows: 3 -> 64, relu. block = 4 slots x 64 couts
__global__ void conv0c_kernel(const float* __restrict__ vs, const int* __restrict__ listF2,
                              const float* __restrict__ agg0c,
                              const float* __restrict__ Ws, const float* __restrict__ Wn,
                              const float* __restrict__ b, const int* __restrict__ cnt,
                              float* __restrict__ x1c) {
    int nF2 = min(cnt[CNT_F2], CAP_F2);
    if ((int)blockIdx.x * 4 >= nF2) return;
    __shared__ float ws_l[192], wn_l[192], b_l[64];
    int tid = threadIdx.x;
    if (tid < 192) { ws_l[tid] = Ws[tid]; wn_l[tid] = Wn[tid]; }
    if (tid < 64) b_l[tid] = b[tid];
    __syncthreads();
    int g = blockIdx.x * 4 + (tid >> 6);
    int j = tid & 63;
    if (g >= nF2) return;
    int n = listF2[g];
    float x0 = vs[n * 3 + 0], x1v = vs[n * 3 + 1], x2v = vs[n * 3 + 2];
    float a0 = agg0c[g * 4 + 0], a1 = agg0c[g * 4 + 1], a2 = agg0c[g * 4 + 2];
    float acc = b_l[j];
    acc = fmaf(x0, ws_l[0 * 64 + j], acc);
    acc = fmaf(x1v, ws_l[1 * 64 + j], acc);
    acc = fmaf(x2v, ws_l[2 * 64 + j], acc);
    acc = fmaf(a0, wn_l[0 * 64 + j], acc);
    acc = fmaf(a1, wn_l[1 * 64 + j], acc);
    acc = fmaf(a2, wn_l[2 * 64 + j], acc);
    x1c[g * 64 + j] = fmaxf(acc, 0.f);
}

// gather agg1 (64ch) per F1 slot: wave per slot, lane = channel
__global__ __launch_bounds__(256) void gather1_kernel(const float* __restrict__ x1c,
                                                      const int* __restrict__ adjF1,
                                                      const int* __restrict__ degF1,
                                                      const int* __restrict__ cnt,
                                                      float* __restrict__ agg1c) {
    int wslot = blockIdx.x * 4 + (threadIdx.x >> 6);
    int lane = threadIdx.x & 63;
    int n = min(cnt[CNT_F1], CAP_F1);
    if (wslot >= n) return;
    int deg = min(degF1[wslot], K_ADJ);
    float acc = 0.f;
    for (int d = 0; d < deg; d++) {
        int src = adjF1[wslot * K_ADJ + d];
        if (src >= 0) acc += x1c[src * 64 + lane];
    }
    agg1c[wslot * 64 + lane] = acc;
}

// gather agg2 (128ch) per boundary slot: wave per slot, 2 channel halves
__global__ __launch_bounds__(256) void gather2_kernel(const float* __restrict__ x2c,
                                                      const int* __restrict__ adjB,
                                                      const int* __restrict__ degB,
                                                      float* __restrict__ agg2c) {
    int wslot = blockIdx.x * 4 + (threadIdx.x >> 6);   // < 1024
    int lane = threadIdx.x & 63;
    int deg = min(degB[wslot], K_ADJ);
    float a0 = 0.f, a1 = 0.f;
    for (int d = 0; d < deg; d++) {
        int src = adjB[wslot * K_ADJ + d];
        if (src >= 0) {
            a0 += x2c[src * 128 + lane];
            a1 += x2c[src * 128 + 64 + lane];
        }
    }
    agg2c[wslot * 128 + lane] = a0;
    agg2c[wslot * 128 + 64 + lane] = a1;
}

// tiled conv: CIN -> COUT, relu. Grid: (row tiles, COUT/64).
// 256 threads = 64 cout-lanes x 4 row-groups; each thread: ROWS/4 rows x 1 cout.
// Weight loads are software-pipelined: UNR=16 c-slices double-buffered in registers
// (32 independent loads in flight per batch), hiding the ~900-cycle cold-miss
// latency that stalled the R12 version (VALUBusy 6%).
template <int CIN, int COUT, int ROWS>
__global__ __launch_bounds__(256) void convT_kernel(
    const float* __restrict__ x, const float* __restrict__ agg,
    const float* __restrict__ Ws, const float* __restrict__ Wn,
    const float* __restrict__ b, float* __restrict__ out,
    const int* __restrict__ idxx, const int* __restrict__ idxa,
    int nrows_max, const int* __restrict__ nrows_dev) {
    const int RPT = ROWS / 4;
    const int C4 = CIN / 4;
    const int UNR = 16;              // CIN % UNR == 0 for 64/128
    __shared__ float xs[ROWS * CIN];
    __shared__ float as[ROWS * CIN];
    int nrows = nrows_max;
    if (nrows_dev) { int nd = nrows_dev[0]; nrows = nd < nrows ? nd : nrows; }
    int gbase = blockIdx.x * ROWS;
    if (gbase >= nrows) return;
    int tid = threadIdx.x;
    int cb = blockIdx.y * 64;
    for (int i = tid; i < ROWS * C4; i += 256) {
        int nl = i / C4, c4 = i % C4;
        int ng = gbase + nl;
        float4 xv = make_float4(0.f, 0.f, 0.f, 0.f);
        float4 av = xv;
        if (ng < nrows) {
            int rowx = idxx ? idxx[ng] : ng;
            int rowa = idxa ? idxa[ng] : ng;
            xv = ((const float4*)x)[rowx * C4 + c4];
            av = ((const float4*)agg)[rowa * C4 + c4];
        }
        ((float4*)xs)[i] = xv;
        ((float4*)as)[i] = av;
    }
    __syncthreads();
    int j = tid & 63, g = tid >> 6;
    const float* Wsp = Ws + cb + j;
    const float* Wnp = Wn + cb + j;
    float acc[RPT];
    float bv = b[cb + j];
    #pragma unroll
    for (int k = 0; k < RPT; k++) acc[k] = bv;
    // prologue: load first weight batch
    float w0[2 * UNR];
    #pragma unroll
    for (int u = 0; u < UNR; u++) {
        w0[u]       = Wsp[u * COUT];
        w0[UNR + u] = Wnp[u * COUT];
    }
    for (int cc = 0; cc < CIN; cc += UNR) {
        float w1[2 * UNR];
        bool more = (cc + UNR) < CIN;
        if (more) {
            #pragma unroll
            for (int u = 0; u < UNR; u++) {
                w1[u]       = Wsp[(cc + UNR + u) * COUT];
                w1[UNR + u] = Wnp[(cc + UNR + u) * COUT];
            }
        }
        #pragma unroll
        for (int u = 0; u < UNR; u++) {
            float wsv = w0[u], wnv = w0[UNR + u];
            #pragma unroll
            for (int k = 0; k < RPT; k++) {
                float xv = xs[(g * RPT + k) * CIN + cc + u];
                float av = as[(g * RPT + k) * CIN + cc + u];
                acc[k] = fmaf(xv, wsv, fmaf(av, wnv, acc[k]));
            }
        }
        if (more) {
            #pragma unroll
            for (int u = 0; u < 2 * UNR; u++) w0[u] = w1[u];
        }
    }
    #pragma unroll
    for (int k = 0; k < RPT; k++) {
        int ng = gbase + g * RPT + k;
        if (ng < nrows) out[ng * COUT + cb + j] = fmaxf(acc[k], 0.f);
    }
}

// pooled sum over 1024 boundary rows of x3b (compact 1024x256)
__global__ void pool_kernel(const float* __restrict__ x3b, float* __restrict__ pooled) {
    int j = threadIdx.x;
    int r0 = blockIdx.x * 32;
    float s = 0.f;
    for (int r = 0; r < 32; r++) s += x3b[(r0 + r) * 256 + j];
    atomicAdd(&pooled[j], s);
}

// head: pooled/1024 -> fc(relu) -> out(12) + bmean broadcast
__global__ void head_kernel(const float* __restrict__ pooled_sum, const float* __restrict__ bmean,
                            const float* __restrict__ Wd, const float* __restrict__ bd,
                            const float* __restrict__ Wo, const float* __restrict__ bo,
                            float* __restrict__ out) {
    __shared__ float p_l[256], h_l[256];
    int tid = threadIdx.x;
    p_l[tid] = pooled_sum[tid] * (1.0f / NB);
    __syncthreads();
    float acc = bd[tid];
    for (int c = 0; c < 256; c++) acc = fmaf(p_l[c], Wd[c * 256 + tid], acc);
    h_l[tid] = fmaxf(acc, 0.f);
    __syncthreads();
    if (tid < 12) {
        float o = bo[tid];
        for (int c = 0; c < 256; c++) o = fmaf(h_l[c], Wo[c * 12 + tid], o);
        out[tid] = o + bmean[tid % 3];
    }
}

extern "C" void kernel_launch(void* const* d_in, const int* in_sizes, int n_in,
                              void* d_out, int out_size, void* d_ws, size_t ws_size,
                              hipStream_t stream) {
    const float* vs    = (const float*)d_in[0];
    const int2*  edges = (const int2*)d_in[1];
    const int*   bidx  = (const int*)d_in[2];
    const float* Ws0 = (const float*)d_in[4];
    const float* Wn0 = (const float*)d_in[5];
    const float* b0  = (const float*)d_in[6];
    const float* Ws1 = (const float*)d_in[7];
    const float* Wn1 = (const float*)d_in[8];
    const float* b1  = (const float*)d_in[9];
    const float* Ws2 = (const float*)d_in[10];
    const float* Wn2 = (const float*)d_in[11];
    const float* b2  = (const float*)d_in[12];
    const float* Wd  = (const float*)d_in[13];
    const float* bd  = (const float*)d_in[14];
    const float* Wo  = (const float*)d_in[15];
    const float* bo  = (const float*)d_in[16];

    float* ws = (float*)d_ws;
    float* x1c    = ws + OFF_X1C;
    float* x2c    = ws + OFF_X2C;
    float* x3b    = ws + OFF_X3B;
    float* agg0c  = ws + OFF_AGG0C;
    float* agg1c  = ws + OFF_AGG1C;
    float* agg2c  = ws + OFF_AGG2C;
    float* pooled = ws + OFF_POOL;
    int*   cnt    = (int*)(ws + OFF_CNT);
    int*   degF2  = (int*)(ws + OFF_DEGF2);
    int*   degF1  = (int*)(ws + OFF_DEGF1);
    int*   degB   = (int*)(ws + OFF_DEGB);
    int*   mF1    = (int*)(ws + OFF_MF1);
    int*   mF2    = (int*)(ws + OFF_MF2);
    int*   slotB  = (int*)(ws + OFF_SLOTB);
    int*   slotF1 = (int*)(ws + OFF_SLOTF1);
    int*   slotF2 = (int*)(ws + OFF_SLOTF2);
    int*   listF1 = (int*)(ws + OFF_LISTF1);
    int*   listF2 = (int*)(ws + OFF_LISTF2);
    int*   adj0   = (int*)(ws + OFF_ADJ0);
    int*   adjF1  = (int*)(ws + OFF_ADJF1);
    int*   adjB   = (int*)(ws + OFF_ADJB);
    int*   idxx2  = (int*)(ws + OFF_IDXX2);
    int*   idxa2  = (int*)(ws + OFF_IDXA2);
    int*   f1f2   = (int*)(ws + OFF_F1F2);
    float* bmean  = ws + OFF_BMEAN;
    float* outp   = (float*)d_out;

    const int EB = (N_EDGES + 255) / 256;
    const int NBLK = (N_NODES + 255) / 256;

    hipMemsetAsync(ws + OFF_POOL, 0, ZERO_BYTES, stream);      // cnt, deg*, marks, pool
    hipMemsetAsync(ws + OFF_SLOTB, 0xFF, FF_BYTES, stream);    // slotB = -1

    bmean_kernel<<<1, 256, 0, stream>>>(vs, bidx, bmean);

    // frontier construction: mark (plain stores) -> compact (block-aggregated alloc)
    mark_b_kernel<<<(NB + 255) / 256, 256, 0, stream>>>(bidx, slotB);
    scan_mark_kernel<<<EB, 256, 0, stream>>>(edges, slotB, mF1);
    compact_kernel<<<NBLK, 256, 0, stream>>>(mF1, slotB, slotF1, listF1,
                                             cnt + CNT_F1, CAP_F1, nullptr);
    scan_mark_kernel<<<EB, 256, 0, stream>>>(edges, slotF1, mF2);
    compact_kernel<<<NBLK, 256, 0, stream>>>(mF2, slotF1, slotF2, listF2,
                                             cnt + CNT_F2, CAP_F2, f1f2);
    build_adj_kernel<<<EB, 256, 0, stream>>>(edges, slotB, slotF1, slotF2,
                                             degF2, adj0, degF1, adjF1, degB, adjB);
    conv2_idx_kernel<<<(NB + 255) / 256, 256, 0, stream>>>(bidx, slotB, slotF1, idxx2, idxa2);

    // layer 0 on F2 (gather, no fp atomics)
    gather0_kernel<<<CAP_F2 / 256, 256, 0, stream>>>(vs, adj0, degF2, cnt, agg0c);
    conv0c_kernel<<<CAP_F2 / 4, 256, 0, stream>>>(vs, listF2, agg0c, Ws0, Wn0, b0, cnt, x1c);

    // layer 1 on F1: 16-row tiles x 2 cout-tiles (~900 active blocks)
    gather1_kernel<<<CAP_F1 / 4, 256, 0, stream>>>(x1c, adjF1, degF1, cnt, agg1c);
    convT_kernel<64, 128, 16><<<dim3(CAP_F1 / 16, 2), 256, 0, stream>>>(
        x1c, agg1c, Ws1, Wn1, b1, x2c, f1f2, nullptr, CAP_F1, cnt + CNT_F1);

    // layer 2 on boundary: 8-row tiles x 4 cout-tiles = 512 blocks (2/CU)
    gather2_kernel<<<NB / 4, 256, 0, stream>>>(x2c, adjB, degB, agg2c);
    convT_kernel<128, 256, 8><<<dim3(NB / 8, 4), 256, 0, stream>>>(
        x2c, agg2c, Ws2, Wn2, b2, x3b, idxx2, idxa2, NB, nullptr);

    // head
    pool_kernel<<<32, 256, 0, stream>>>(x3b, pooled);
    head_kernel<<<1, 256, 0, stream>>>(pooled, bmean, Wd, bd, Wo, bo, outp);
}